// Round 5
// baseline (695.368 us; speedup 1.0000x reference)
//
#include <hip/hip_runtime.h>

// approxmatch EMD (Fan et al.) on MI355X, B=4, N=M=4096, layout (B,3,N).
// Round 11: staging-overlap round.
// R4 post-mortem: barrier+L2 fixes landed (1552->633us, VALUBusy 54.7%,
// FETCH 15MB) but 45% of cycles are still stall: 8 tile-stages per phase with
// 2 syncthreads each and no global-load/compute overlap (~340 serial stage
// boundaries across 21 phases, all waves of a block stalling together).
// Fix: reg-staged double-buffered LDS tiles. Per tile: issue next tile's
// global loads into regs BEFORE computing current tile (LLC latency hides
// under ~1.6us compute), ds_write to the alternate buffer after compute,
// ONE syncthreads per tile. Compute order per wave unchanged -> bitwise
// identical. Smem 20.5KB (still >=4 blocks/CU). Barrier, versioned buffers,
// CULL thresholds all unchanged from R4.

#define NPTS 4096
#define BATCH 4
#define EMD_EPS 1e-9f
#define TILE 512         // columns staged per LDS stage
#define NTILE (NPTS / TILE)        // 8
#define RPW 4            // rows per wave, in registers
#define THREADS 256      // 4 waves
#define RPB 16           // rows per block = 4 waves * RPW
#define NBLK (NPTS / RPB)          // 256 row-blocks per batch
#define NBLK_TOTAL (NBLK * BATCH)  // 1024 blocks = 4 per CU

#define GRP_SHIFT 4
#define GRP_SIZE (1 << GRP_SHIFT)      // 16 blocks per barrier group
#define NGRP (NBLK_TOTAL / GRP_SIZE)   // 64 groups
#define BAR_STRIDE 4352                // u32 per barrier instance
#define NB_BAR 24                      // 21 used

#define CULL_FULL -160.0f  // exp2(x) == +0.0f for all x < -160
#define CULL_PART -40.0f   // ((2^x)^2)^2 == +0.0f for all x < -40

typedef float v2f __attribute__((ext_vector_type(2)));

struct Params {
    const float* xyz1;
    const float* xyz2;
    float* remainL;          // block-private: normal access
    float* cost_part;        // agent (cross-XCD read at finalize)
    float* S_L;              // agent
    float* out;
    unsigned* bar;
    float* ratioL[10];       // versioned: ratioL[t] written end of sweep t-1
    float* ratioR[9];        // versioned per sweep
    float* remainR[9];       // versioned per sweep
    float ls2[10];
};

struct Smem {
    float4 sA[2][TILE / 2];
    float4 sB[2][TILE / 2];
    float2 sC[2][TILE / 2];
    float  s_cost[THREADS / 64];
};

// ---------------- agent-scope (LLC-routed, L2-bypassing) accessors
__device__ __forceinline__ float aload(const float* p_) {
    return __hip_atomic_load((float*)p_, __ATOMIC_RELAXED, __HIP_MEMORY_SCOPE_AGENT);
}
__device__ __forceinline__ void astore(float* p_, float v) {
    __hip_atomic_store(p_, v, __ATOMIC_RELAXED, __HIP_MEMORY_SCOPE_AGENT);
}
__device__ __forceinline__ unsigned au_add(unsigned* p_, unsigned v) {
    return __hip_atomic_fetch_add(p_, v, __ATOMIC_RELAXED, __HIP_MEMORY_SCOPE_AGENT);
}
__device__ __forceinline__ unsigned au_load(const unsigned* p_) {
    return __hip_atomic_load((unsigned*)p_, __ATOMIC_RELAXED, __HIP_MEMORY_SCOPE_AGENT);
}
__device__ __forceinline__ void au_store(unsigned* p_, unsigned v) {
    __hip_atomic_store(p_, v, __ATOMIC_RELAXED, __HIP_MEMORY_SCOPE_AGENT);
}

// ---------------- two-level grid barrier (relaxed agent atomics, striped)
__device__ __forceinline__ void gsync(unsigned* barbase, int idx) {
    __syncthreads();
    if (threadIdx.x == 0) {
        unsigned* B = barbase + idx * BAR_STRIDE;
        const int bid = blockIdx.y * NBLK + blockIdx.x;
        const int grp = bid >> GRP_SHIFT;
        unsigned* gc   = B + grp * 32;
        unsigned* root = B + NGRP * 32;
        unsigned* gr   = B + NGRP * 32 + 32 + grp * 32;
        unsigned old = au_add(gc, 1u);
        if (old == GRP_SIZE - 1u) {
            unsigned r = au_add(root, 1u) + 1u;
            while (r < (unsigned)NGRP) {
                __builtin_amdgcn_s_sleep(4);
                r = au_load(root);
            }
            au_store(gr, 1u);
        } else {
            while (au_load(gr) == 0u)
                __builtin_amdgcn_s_sleep(4);
        }
        asm volatile("" ::: "memory");
    }
    __syncthreads();
}

__device__ __forceinline__ float fexp2(float x) {
#if __has_builtin(__builtin_amdgcn_exp2f)
    return __builtin_amdgcn_exp2f(x);
#else
    return exp2f(x);
#endif
}
__device__ __forceinline__ float fsqrt(float x) {
#if __has_builtin(__builtin_amdgcn_sqrtf)
    return __builtin_amdgcn_sqrtf(x);
#else
    return __sqrtf(x);
#endif
}

__device__ __forceinline__ float wave_reduce(float v) {
    v += __shfl_xor(v, 32);
    v += __shfl_xor(v, 16);
    v += __shfl_xor(v, 8);
    v += __shfl_xor(v, 4);
    v += __shfl_xor(v, 2);
    v += __shfl_xor(v, 1);
    return v;
}

// ---------------------------------------------------------------- phase: sweep-0 ratioL
__device__ __forceinline__ void phase_ratioL0(Smem& sm, const Params& p, float ls2,
                                              float* __restrict__ rLout) {
    const int b = blockIdx.y;
    const int tid = threadIdx.x;
    const int wave = tid >> 6;
    const int lane = tid & 63;
    const int row0 = blockIdx.x * RPB + wave * RPW;

    const float* x1 = p.xyz1 + b * 3 * NPTS;
    const float* x2 = p.xyz2 + b * 3 * NPTS;
    const float2* x2x = (const float2*)(x2);
    const float2* x2y = (const float2*)(x2 + NPTS);
    const float2* x2z = (const float2*)(x2 + 2 * NPTS);

    float px[RPW], py[RPW], pz[RPW];
    v2f acc[RPW];
#pragma unroll
    for (int r = 0; r < RPW; ++r) {
        px[r] = x1[row0 + r];
        py[r] = x1[NPTS + row0 + r];
        pz[r] = x1[2 * NPTS + row0 + r];
        acc[r] = (v2f)(0.0f);
    }
    float2 g0, g1, g2;
    // tid in [0,256) == TILE/2 -> each thread stages exactly one entry
    {
        int e = tid;
        g0 = x2x[e]; g1 = x2y[e]; g2 = x2z[e];
        sm.sA[0][tid] = make_float4(g0.x, g0.y, g1.x, g1.y);
        sm.sC[0][tid] = g2;
    }
    __syncthreads();
    for (int kt = 0; kt < NTILE; ++kt) {
        const int cur = kt & 1;
        if (kt + 1 < NTILE) {
            int e = (kt + 1) * (TILE / 2) + tid;
            g0 = x2x[e]; g1 = x2y[e]; g2 = x2z[e];
        }
#pragma unroll 2
        for (int j = 0; j < TILE / 128; ++j) {
            float4 a = sm.sA[cur][lane + 64 * j];
            float2 z = sm.sC[cur][lane + 64 * j];
            v2f ax = {a.x, a.y}, ay = {a.z, a.w}, az = {z.x, z.y};
#pragma unroll
            for (int r = 0; r < RPW; ++r) {
                v2f dx = px[r] - ax, dy = py[r] - ay, dz = pz[r] - az;
                v2f d = dx * dx + dy * dy + dz * dz;
                v2f sd = ls2 * d;
                if (!__all(fmaxf(sd.x, sd.y) < CULL_FULL)) {
                    v2f e2 = {fexp2(sd.x), fexp2(sd.y)};
                    acc[r] += e2;
                }
            }
        }
        if (kt + 1 < NTILE) {
            sm.sA[cur ^ 1][tid] = make_float4(g0.x, g0.y, g1.x, g1.y);
            sm.sC[cur ^ 1][tid] = g2;
            __syncthreads();
        }
    }
#pragma unroll
    for (int r = 0; r < RPW; ++r) {
        float s = wave_reduce(acc[r].x + acc[r].y);
        if (lane == 0) {
            int idx = b * NPTS + row0 + r;
            astore(&rLout[idx], 1.0f / (EMD_EPS + s));
            p.remainL[idx] = 1.0f;
        }
    }
}

// ---------------------------------------------------------------- phase: ratioR (sweep t)
template <bool CULL>
__device__ __forceinline__ void phase_ratioR(Smem& sm, const Params& p, float ls2,
                                             const float* __restrict__ rL,
                                             const float* __restrict__ rRprev,
                                             float* __restrict__ rRout,
                                             float* __restrict__ remROut) {
    const int b = blockIdx.y;
    const int tid = threadIdx.x;
    const int wave = tid >> 6;
    const int lane = tid & 63;
    const int col0 = blockIdx.x * RPB + wave * RPW;

    const float* x1 = p.xyz1 + b * 3 * NPTS;
    const float* x2 = p.xyz2 + b * 3 * NPTS;
    const float2* x1x = (const float2*)(x1);
    const float2* x1y = (const float2*)(x1 + NPTS);
    const float2* x1z = (const float2*)(x1 + 2 * NPTS);
    const float2* wLv = (const float2*)(rL + b * NPTS);

    float px[RPW], py[RPW], pz[RPW];
    v2f acc[RPW];
#pragma unroll
    for (int r = 0; r < RPW; ++r) {
        px[r] = x2[col0 + r];
        py[r] = x2[NPTS + col0 + r];
        pz[r] = x2[2 * NPTS + col0 + r];
        acc[r] = (v2f)(0.0f);
    }
    float2 g0, g1, g2, g3;
    {
        int e = tid;
        g0 = x1x[e]; g1 = x1y[e]; g2 = x1z[e]; g3 = wLv[e];
        sm.sA[0][tid] = make_float4(g0.x, g0.y, g1.x, g1.y);
        sm.sB[0][tid] = make_float4(g2.x, g2.y, g3.x, g3.y);
    }
    __syncthreads();
    for (int kt = 0; kt < NTILE; ++kt) {
        const int cur = kt & 1;
        if (kt + 1 < NTILE) {
            int e = (kt + 1) * (TILE / 2) + tid;
            g0 = x1x[e]; g1 = x1y[e]; g2 = x1z[e]; g3 = wLv[e];
        }
#pragma unroll 2
        for (int j = 0; j < TILE / 128; ++j) {
            float4 a = sm.sA[cur][lane + 64 * j];
            float4 bq = sm.sB[cur][lane + 64 * j];
            v2f ax = {a.x, a.y}, ay = {a.z, a.w};
            v2f az = {bq.x, bq.y}, aw = {bq.z, bq.w};
#pragma unroll
            for (int r = 0; r < RPW; ++r) {
                v2f dx = px[r] - ax, dy = py[r] - ay, dz = pz[r] - az;
                v2f d = dx * dx + dy * dy + dz * dz;
                v2f sd = ls2 * d;
                bool live = true;
                if (CULL) live = !__all(fmaxf(sd.x, sd.y) < CULL_FULL);
                if (live) {
                    v2f e2 = {fexp2(sd.x), fexp2(sd.y)};
                    acc[r] += e2 * aw;
                }
            }
        }
        if (kt + 1 < NTILE) {
            sm.sA[cur ^ 1][tid] = make_float4(g0.x, g0.y, g1.x, g1.y);
            sm.sB[cur ^ 1][tid] = make_float4(g2.x, g2.y, g3.x, g3.y);
            __syncthreads();
        }
    }
#pragma unroll
    for (int r = 0; r < RPW; ++r) {
        float s = wave_reduce(acc[r].x + acc[r].y);
        if (lane == 0) {
            int idx = b * NPTS + col0 + r;
            float rv = rRprev ? rRprev[idx] : 1.0f;
            float sumr = rv * s;
            float cons = fminf(rv / (sumr + EMD_EPS), 1.0f);
            astore(&rRout[idx], cons * rv);
            astore(&remROut[idx], fmaxf(0.0f, rv - sumr));
        }
    }
}

// ---------------------------------------------------------------- phase: cost(t) + ratioL(t+1)
template <bool SQ, bool CULL>
__device__ __forceinline__ void phase_cost(Smem& sm, const Params& p,
                                           float ls2, float ls2n,
                                           const float* __restrict__ rR,
                                           const float* __restrict__ w2,
                                           const float* __restrict__ rLin,
                                           float* __restrict__ rLout,
                                           int initCost) {
    const int b = blockIdx.y;
    const int tid = threadIdx.x;
    const int wave = tid >> 6;
    const int lane = tid & 63;
    const int row0 = blockIdx.x * RPB + wave * RPW;

    const float* x1 = p.xyz1 + b * 3 * NPTS;
    const float* x2 = p.xyz2 + b * 3 * NPTS;
    const float2* x2x = (const float2*)(x2);
    const float2* x2y = (const float2*)(x2 + NPTS);
    const float2* x2z = (const float2*)(x2 + 2 * NPTS);
    const float2* wRv = (const float2*)(rR + b * NPTS);
    const float2* w2v = (const float2*)(w2 + b * NPTS);

    float px[RPW], py[RPW], pz[RPW];
    v2f acc_a[RPW], acc_c[RPW], acc_s[RPW];
#pragma unroll
    for (int r = 0; r < RPW; ++r) {
        px[r] = x1[row0 + r];
        py[r] = x1[NPTS + row0 + r];
        pz[r] = x1[2 * NPTS + row0 + r];
        acc_a[r] = (v2f)(0.0f);
        acc_c[r] = (v2f)(0.0f);
        acc_s[r] = (v2f)(0.0f);
    }
    float2 g0, g1, g2, g3, g4;
    {
        int e = tid;
        g0 = x2x[e]; g1 = x2y[e]; g2 = x2z[e]; g3 = wRv[e]; g4 = w2v[e];
        sm.sA[0][tid] = make_float4(g0.x, g0.y, g1.x, g1.y);
        sm.sB[0][tid] = make_float4(g2.x, g2.y, g3.x, g3.y);
        sm.sC[0][tid] = g4;
    }
    __syncthreads();
    for (int kt = 0; kt < NTILE; ++kt) {
        const int cur = kt & 1;
        if (kt + 1 < NTILE) {
            int e = (kt + 1) * (TILE / 2) + tid;
            g0 = x2x[e]; g1 = x2y[e]; g2 = x2z[e]; g3 = wRv[e]; g4 = w2v[e];
        }
#pragma unroll 2
        for (int j = 0; j < TILE / 128; ++j) {
            float4 a = sm.sA[cur][lane + 64 * j];
            float4 bq = sm.sB[cur][lane + 64 * j];
            float2 c = sm.sC[cur][lane + 64 * j];
            v2f ax = {a.x, a.y}, ay = {a.z, a.w};
            v2f az = {bq.x, bq.y}, wr = {bq.z, bq.w};
            v2f cw = {c.x, c.y};
#pragma unroll
            for (int r = 0; r < RPW; ++r) {
                v2f dx = px[r] - ax, dy = py[r] - ay, dz = pz[r] - az;
                v2f d = dx * dx + dy * dy + dz * dz;
                if (SQ) {
                    v2f sd = ls2n * d;
                    bool fullskip = false, partskip = false;
                    if (CULL) {
                        float mx = fmaxf(sd.x, sd.y);
                        fullskip = __all(mx < CULL_FULL);
                        partskip = __all(mx < CULL_PART);
                    }
                    if (!fullskip) {
                        v2f e2 = {fexp2(sd.x), fexp2(sd.y)};
                        acc_s[r] += e2 * cw;
                        if (!partskip) {
                            v2f e4 = e2 * e2;
                            v2f er = (e4 * e4) * wr;
                            acc_a[r] += er;
                            v2f sq = {fsqrt(d.x), fsqrt(d.y)};
                            acc_c[r] += er * sq;
                        }
                    }
                } else {
                    v2f sd = ls2 * d;
                    v2f e1 = {fexp2(sd.x), fexp2(sd.y)};
                    v2f er = e1 * wr;
                    acc_s[r] += cw;   // e2 == 1 when ls2n == 0
                    acc_a[r] += er;
                    v2f sq = {fsqrt(d.x), fsqrt(d.y)};
                    acc_c[r] += er * sq;
                }
            }
        }
        if (kt + 1 < NTILE) {
            sm.sA[cur ^ 1][tid] = make_float4(g0.x, g0.y, g1.x, g1.y);
            sm.sB[cur ^ 1][tid] = make_float4(g2.x, g2.y, g3.x, g3.y);
            sm.sC[cur ^ 1][tid] = g4;
            __syncthreads();
        }
    }
    float wcost = 0.0f;
#pragma unroll
    for (int r = 0; r < RPW; ++r) {
        float sa = wave_reduce(acc_a[r].x + acc_a[r].y);
        float sc = wave_reduce(acc_c[r].x + acc_c[r].y);
        float ss = wave_reduce(acc_s[r].x + acc_s[r].y);
        if (lane == 0) {
            int idx = b * NPTS + row0 + r;
            float rl = rLin[idx];
            float rem = fmaxf(0.0f, p.remainL[idx] - rl * sa);
            p.remainL[idx] = rem;
            astore(&rLout[idx], rem / (EMD_EPS + ss));
            wcost = fmaf(rl, sc, wcost);
        }
    }
    if (lane == 0) sm.s_cost[wave] = wcost;
    __syncthreads();
    if (tid == 0) {
        float t = sm.s_cost[0] + sm.s_cost[1] + sm.s_cost[2] + sm.s_cost[3];
        int ci = b * NBLK + blockIdx.x;
        astore(&p.cost_part[ci], initCost ? t : aload(&p.cost_part[ci]) + t);
    }
}

// ---------------------------------------------------------------- phase: sum ratioL[9]
__device__ __forceinline__ void phase_sum_ratioL(Smem& sm, const Params& p,
                                                 const float* __restrict__ rL) {
    if (blockIdx.x != 0) return;
    const int b = blockIdx.y;
    const int tid = threadIdx.x;
    float s = 0.0f;
    for (int i = tid; i < NPTS; i += 256) s += rL[b * NPTS + i];
    s = wave_reduce(s);
    if ((tid & 63) == 0) sm.s_cost[tid >> 6] = s;
    __syncthreads();
    if (tid == 0)
        astore(&p.S_L[b], sm.s_cost[0] + sm.s_cost[1] + sm.s_cost[2] + sm.s_cost[3]);
}

// ---------------------------------------------------------------- phase: level-0 cost
__device__ __forceinline__ void phase_cost_l0(Smem& sm, const Params& p,
                                              const float* __restrict__ w2,
                                              const float* __restrict__ rL) {
    const int b = blockIdx.y;
    const int tid = threadIdx.x;
    const int wave = tid >> 6;
    const int lane = tid & 63;
    const int row0 = blockIdx.x * RPB + wave * RPW;
    const float sL = aload(&p.S_L[b]);

    const float* x1 = p.xyz1 + b * 3 * NPTS;
    const float* x2 = p.xyz2 + b * 3 * NPTS;
    const float2* x2x = (const float2*)(x2);
    const float2* x2y = (const float2*)(x2 + NPTS);
    const float2* x2z = (const float2*)(x2 + 2 * NPTS);
    const float2* wRv = (const float2*)(w2 + b * NPTS);

    float px[RPW], py[RPW], pz[RPW];
    v2f acc_c[RPW];
#pragma unroll
    for (int r = 0; r < RPW; ++r) {
        px[r] = x1[row0 + r];
        py[r] = x1[NPTS + row0 + r];
        pz[r] = x1[2 * NPTS + row0 + r];
        acc_c[r] = (v2f)(0.0f);
    }
    float2 g0, g1, g2, g3;
    {
        int e = tid;
        g0 = x2x[e]; g1 = x2y[e]; g2 = x2z[e]; g3 = wRv[e];
        float wr0 = fminf(g3.x / (g3.x * sL + EMD_EPS), 1.0f) * g3.x;
        float wr1 = fminf(g3.y / (g3.y * sL + EMD_EPS), 1.0f) * g3.y;
        sm.sA[0][tid] = make_float4(g0.x, g0.y, g1.x, g1.y);
        sm.sB[0][tid] = make_float4(g2.x, g2.y, wr0, wr1);
    }
    __syncthreads();
    for (int kt = 0; kt < NTILE; ++kt) {
        const int cur = kt & 1;
        if (kt + 1 < NTILE) {
            int e = (kt + 1) * (TILE / 2) + tid;
            g0 = x2x[e]; g1 = x2y[e]; g2 = x2z[e]; g3 = wRv[e];
        }
#pragma unroll 2
        for (int j = 0; j < TILE / 128; ++j) {
            float4 a = sm.sA[cur][lane + 64 * j];
            float4 bq = sm.sB[cur][lane + 64 * j];
            v2f ax = {a.x, a.y}, ay = {a.z, a.w};
            v2f az = {bq.x, bq.y}, wr = {bq.z, bq.w};
#pragma unroll
            for (int r = 0; r < RPW; ++r) {
                v2f dx = px[r] - ax, dy = py[r] - ay, dz = pz[r] - az;
                v2f d = dx * dx + dy * dy + dz * dz;
                v2f sq = {fsqrt(d.x), fsqrt(d.y)};
                acc_c[r] += wr * sq;
            }
        }
        if (kt + 1 < NTILE) {
            float wr0 = fminf(g3.x / (g3.x * sL + EMD_EPS), 1.0f) * g3.x;
            float wr1 = fminf(g3.y / (g3.y * sL + EMD_EPS), 1.0f) * g3.y;
            sm.sA[cur ^ 1][tid] = make_float4(g0.x, g0.y, g1.x, g1.y);
            sm.sB[cur ^ 1][tid] = make_float4(g2.x, g2.y, wr0, wr1);
            __syncthreads();
        }
    }
    float wcost = 0.0f;
#pragma unroll
    for (int r = 0; r < RPW; ++r) {
        float sc = wave_reduce(acc_c[r].x + acc_c[r].y);
        if (lane == 0)
            wcost = fmaf(rL[b * NPTS + row0 + r], sc, wcost);
    }
    if (lane == 0) sm.s_cost[wave] = wcost;
    __syncthreads();
    if (tid == 0) {
        float t = sm.s_cost[0] + sm.s_cost[1] + sm.s_cost[2] + sm.s_cost[3];
        int ci = b * NBLK + blockIdx.x;
        astore(&p.cost_part[ci], aload(&p.cost_part[ci]) + t);
    }
}

// ---------------------------------------------------------------- phase: finalize
__device__ __forceinline__ void phase_final(Smem& sm, const Params& p) {
    if (blockIdx.x != 0 || blockIdx.y != 0) return;
    const int tid = threadIdx.x;
    float s = 0.0f;
    for (int i = tid; i < BATCH * NBLK; i += 256) s += aload(&p.cost_part[i]);
    s = wave_reduce(s);
    if ((tid & 63) == 0) sm.s_cost[tid >> 6] = s;
    __syncthreads();
    if (tid == 0)
        p.out[0] = (sm.s_cost[0] + sm.s_cost[1] + sm.s_cost[2] + sm.s_cost[3]) /
                   ((float)NPTS * (float)BATCH);
}

// ---------------------------------------------------------------- unified persistent kernel
__global__ __launch_bounds__(THREADS, 4) void k_emd_all(Params p) {
    __shared__ Smem sm;
    int bi = 0;
    phase_ratioL0(sm, p, p.ls2[0], p.ratioL[0]);
    gsync(p.bar, bi++);
    for (int t = 0; t < 9; ++t) {
        const float* rRprev = (t == 0) ? nullptr : p.remainR[t - 1];
        if (t < 4)
            phase_ratioR<true>(sm, p, p.ls2[t], p.ratioL[t], rRprev,
                               p.ratioR[t], p.remainR[t]);
        else
            phase_ratioR<false>(sm, p, p.ls2[t], p.ratioL[t], rRprev,
                                p.ratioR[t], p.remainR[t]);
        gsync(p.bar, bi++);
        if (t < 4)
            phase_cost<true, true>(sm, p, p.ls2[t], p.ls2[t + 1], p.ratioR[t],
                                   p.remainR[t], p.ratioL[t], p.ratioL[t + 1], t == 0);
        else if (t < 8)
            phase_cost<true, false>(sm, p, p.ls2[t], p.ls2[t + 1], p.ratioR[t],
                                    p.remainR[t], p.ratioL[t], p.ratioL[t + 1], 0);
        else
            phase_cost<false, false>(sm, p, p.ls2[8], 0.0f, p.ratioR[8],
                                     p.remainR[8], p.ratioL[8], p.ratioL[9], 0);
        gsync(p.bar, bi++);
    }
    phase_sum_ratioL(sm, p, p.ratioL[9]);
    gsync(p.bar, bi++);
    phase_cost_l0(sm, p, p.remainR[8], p.ratioL[9]);
    gsync(p.bar, bi++);
    phase_final(sm, p);
}

// ---------------------------------------------------------------- barrier init
__global__ void k_zero(unsigned* bar) {
    const int n = NB_BAR * BAR_STRIDE;
    for (int i = blockIdx.x * 256 + threadIdx.x; i < n; i += gridDim.x * 256)
        __hip_atomic_store(&bar[i], 0u, __ATOMIC_RELAXED, __HIP_MEMORY_SCOPE_AGENT);
}

// ---------------------------------------------------------------- fallback wrappers
__global__ __launch_bounds__(THREADS, 4) void kw_ratioL0(Params p) {
    __shared__ Smem sm;
    phase_ratioL0(sm, p, p.ls2[0], p.ratioL[0]);
}
__global__ __launch_bounds__(THREADS, 4) void kw_ratioR(Params p, int t) {
    __shared__ Smem sm;
    const float* rRprev = (t == 0) ? nullptr : p.remainR[t - 1];
    if (t < 4) phase_ratioR<true>(sm, p, p.ls2[t], p.ratioL[t], rRprev,
                                  p.ratioR[t], p.remainR[t]);
    else       phase_ratioR<false>(sm, p, p.ls2[t], p.ratioL[t], rRprev,
                                   p.ratioR[t], p.remainR[t]);
}
__global__ __launch_bounds__(THREADS, 4) void kw_cost(Params p, int t) {
    __shared__ Smem sm;
    if (t < 4)
        phase_cost<true, true>(sm, p, p.ls2[t], p.ls2[t + 1], p.ratioR[t],
                               p.remainR[t], p.ratioL[t], p.ratioL[t + 1], t == 0);
    else if (t < 8)
        phase_cost<true, false>(sm, p, p.ls2[t], p.ls2[t + 1], p.ratioR[t],
                                p.remainR[t], p.ratioL[t], p.ratioL[t + 1], 0);
    else
        phase_cost<false, false>(sm, p, p.ls2[8], 0.0f, p.ratioR[8],
                                 p.remainR[8], p.ratioL[8], p.ratioL[9], 0);
}
__global__ __launch_bounds__(THREADS, 4) void kw_sum(Params p) {
    __shared__ Smem sm;
    phase_sum_ratioL(sm, p, p.ratioL[9]);
}
__global__ __launch_bounds__(THREADS, 4) void kw_cost_l0(Params p) {
    __shared__ Smem sm;
    phase_cost_l0(sm, p, p.remainR[8], p.ratioL[9]);
}
__global__ __launch_bounds__(THREADS, 4) void kw_final(Params p) {
    __shared__ Smem sm;
    phase_final(sm, p);
}

extern "C" void kernel_launch(void* const* d_in, const int* in_sizes, int n_in,
                              void* d_out, int out_size, void* d_ws, size_t ws_size,
                              hipStream_t stream) {
    Params p;
    p.xyz1 = (const float*)d_in[0];
    p.xyz2 = (const float*)d_in[1];
    const int BN = BATCH * NPTS;              // 16384 floats per buffer
    const int BUF = BN + 1024;                // + 4KB pad between buffers
    float* ws = (float*)d_ws;
    p.remainL   = ws;                         // BN, block-private
    p.cost_part = ws + BN;                    // 1024
    p.S_L       = p.cost_part + 2048;         // BATCH
    p.bar       = (unsigned*)(p.S_L + 256);   // NB_BAR * BAR_STRIDE u32
    float* vbase = (float*)(p.bar + NB_BAR * BAR_STRIDE) + 256;
    for (int t = 0; t < 10; ++t) p.ratioL[t]  = vbase + t * BUF;
    for (int t = 0; t < 9; ++t)  p.ratioR[t]  = vbase + (10 + t) * BUF;
    for (int t = 0; t < 9; ++t)  p.remainR[t] = vbase + (19 + t) * BUF;
    p.out = (float*)d_out;

    static const double levels[10] = {
        -16384.0, -4096.0, -1024.0, -256.0, -64.0,
        -16.0, -4.0, -1.0, -0.25, 0.0};
    for (int t = 0; t < 10; ++t)
        p.ls2[t] = (float)(levels[t] * 1.4426950408889634);

    dim3 grid(NBLK, BATCH), blk(THREADS);

    static int coop_ok = -1;
    if (coop_ok < 0) {
        int v = 0;
        hipDeviceGetAttribute(&v, hipDeviceAttributeCooperativeLaunch, 0);
        coop_ok = v;
    }

    hipError_t err = hipErrorUnknown;
    if (coop_ok) {
        k_zero<<<64, 256, 0, stream>>>(p.bar);
        void* args[] = {(void*)&p};
        err = hipLaunchCooperativeKernel((void*)k_emd_all, grid, blk, args, 0, stream);
    }
    if (err != hipSuccess) {
        kw_ratioL0<<<grid, blk, 0, stream>>>(p);
        for (int t = 0; t < 9; ++t) {
            kw_ratioR<<<grid, blk, 0, stream>>>(p, t);
            kw_cost<<<grid, blk, 0, stream>>>(p, t);
        }
        kw_sum<<<dim3(1, BATCH), blk, 0, stream>>>(p);
        kw_cost_l0<<<grid, blk, 0, stream>>>(p);
        kw_final<<<dim3(1, 1), blk, 0, stream>>>(p);
    }
}

// Round 8
// 655.681 us; speedup vs baseline: 1.0605x; 1.0605x over previous
//
#include <hip/hip_runtime.h>

// approxmatch EMD (Fan et al.) on MI355X, B=4, N=M=4096, layout (B,3,N).
// Round 14: recovery round — revert to the R4-proven structure.
// R6/R7 post-mortem: the global_load_lds redesign produced an intermittent
// race (R6 tripwire) then a dead launch (R7: out==0 -> absmax == bf16(ref)).
// Two failed rounds on an unproven mechanism vs R4's 3-round-proven base.
// This round: R4 byte-for-byte (plain staged loads, 2 syncthreads/tile,
// two-level barrier, versioned buffers, static+fallback launcher) with ONE
// safe change: TILE 512 -> 1024. Halves stage boundaries per phase (8 -> 4);
// LDS 10.25 -> 20.5KB (still 4 blocks/CU; launch_bounds is the binder).
// Bitwise-identical: a 1024-tile is two R4 tiles concatenated -- the staged
// column sequence and per-row accumulation order are unchanged.

#define NPTS 4096
#define BATCH 4
#define EMD_EPS 1e-9f
#define TILE 1024        // columns staged per LDS stage (R4: 512)
#define RPW 4            // rows per wave, in registers
#define THREADS 256      // 4 waves
#define RPB 16           // rows per block = 4 waves * RPW
#define NBLK (NPTS / RPB)          // 256 row-blocks per batch
#define NBLK_TOTAL (NBLK * BATCH)  // 1024 blocks = 4 per CU

#define GRP_SHIFT 4
#define GRP_SIZE (1 << GRP_SHIFT)      // 16 blocks per barrier group
#define NGRP (NBLK_TOTAL / GRP_SIZE)   // 64 groups
#define BAR_STRIDE 4352                // u32 per barrier instance
#define NB_BAR 24                      // 21 used

#define CULL_FULL -160.0f  // exp2(x) == +0.0f for all x < -160
#define CULL_PART -40.0f   // ((2^x)^2)^2 == +0.0f for all x < -40

typedef float v2f __attribute__((ext_vector_type(2)));

struct Params {
    const float* xyz1;
    const float* xyz2;
    float* remainL;          // block-private: normal access
    float* cost_part;        // agent (cross-XCD read at finalize)
    float* S_L;              // agent
    float* out;
    unsigned* bar;
    float* ratioL[10];       // versioned: ratioL[t] written end of sweep t-1
    float* ratioR[9];        // versioned per sweep
    float* remainR[9];       // versioned per sweep
    float ls2[10];
};

struct Smem {
    float4 sA[TILE / 2];
    float4 sB[TILE / 2];
    float2 sC[TILE / 2];
    float  s_cost[THREADS / 64];
};

// ---------------- agent-scope (LLC-routed, L2-bypassing) accessors
__device__ __forceinline__ float aload(const float* p_) {
    return __hip_atomic_load((float*)p_, __ATOMIC_RELAXED, __HIP_MEMORY_SCOPE_AGENT);
}
__device__ __forceinline__ void astore(float* p_, float v) {
    __hip_atomic_store(p_, v, __ATOMIC_RELAXED, __HIP_MEMORY_SCOPE_AGENT);
}
__device__ __forceinline__ unsigned au_add(unsigned* p_, unsigned v) {
    return __hip_atomic_fetch_add(p_, v, __ATOMIC_RELAXED, __HIP_MEMORY_SCOPE_AGENT);
}
__device__ __forceinline__ unsigned au_load(const unsigned* p_) {
    return __hip_atomic_load((unsigned*)p_, __ATOMIC_RELAXED, __HIP_MEMORY_SCOPE_AGENT);
}
__device__ __forceinline__ void au_store(unsigned* p_, unsigned v) {
    __hip_atomic_store(p_, v, __ATOMIC_RELAXED, __HIP_MEMORY_SCOPE_AGENT);
}

// ---------------- two-level grid barrier (relaxed agent atomics, striped)
__device__ __forceinline__ void gsync(unsigned* barbase, int idx) {
    __syncthreads();
    if (threadIdx.x == 0) {
        unsigned* B = barbase + idx * BAR_STRIDE;
        const int bid = blockIdx.y * NBLK + blockIdx.x;
        const int grp = bid >> GRP_SHIFT;
        unsigned* gc   = B + grp * 32;
        unsigned* root = B + NGRP * 32;
        unsigned* gr   = B + NGRP * 32 + 32 + grp * 32;
        unsigned old = au_add(gc, 1u);
        if (old == GRP_SIZE - 1u) {
            unsigned r = au_add(root, 1u) + 1u;
            while (r < (unsigned)NGRP) {
                __builtin_amdgcn_s_sleep(4);
                r = au_load(root);
            }
            au_store(gr, 1u);
        } else {
            while (au_load(gr) == 0u)
                __builtin_amdgcn_s_sleep(4);
        }
        asm volatile("" ::: "memory");
    }
    __syncthreads();
}

__device__ __forceinline__ float fexp2(float x) {
#if __has_builtin(__builtin_amdgcn_exp2f)
    return __builtin_amdgcn_exp2f(x);
#else
    return exp2f(x);
#endif
}
__device__ __forceinline__ float fsqrt(float x) {
#if __has_builtin(__builtin_amdgcn_sqrtf)
    return __builtin_amdgcn_sqrtf(x);
#else
    return __sqrtf(x);
#endif
}

__device__ __forceinline__ float wave_reduce(float v) {
    v += __shfl_xor(v, 32);
    v += __shfl_xor(v, 16);
    v += __shfl_xor(v, 8);
    v += __shfl_xor(v, 4);
    v += __shfl_xor(v, 2);
    v += __shfl_xor(v, 1);
    return v;
}

// ---------------------------------------------------------------- phase: sweep-0 ratioL
__device__ __forceinline__ void phase_ratioL0(Smem& sm, const Params& p, float ls2,
                                              float* __restrict__ rLout) {
    const int b = blockIdx.y;
    const int tid = threadIdx.x;
    const int wave = tid >> 6;
    const int lane = tid & 63;
    const int row0 = blockIdx.x * RPB + wave * RPW;

    const float* x1 = p.xyz1 + b * 3 * NPTS;
    const float* x2 = p.xyz2 + b * 3 * NPTS;
    const float2* x2x = (const float2*)(x2);
    const float2* x2y = (const float2*)(x2 + NPTS);
    const float2* x2z = (const float2*)(x2 + 2 * NPTS);

    float px[RPW], py[RPW], pz[RPW];
    v2f acc[RPW];
#pragma unroll
    for (int r = 0; r < RPW; ++r) {
        px[r] = x1[row0 + r];
        py[r] = x1[NPTS + row0 + r];
        pz[r] = x1[2 * NPTS + row0 + r];
        acc[r] = (v2f)(0.0f);
    }
    for (int c0 = 0; c0 < NPTS; c0 += TILE) {
        __syncthreads();
        for (int i = tid; i < TILE / 2; i += THREADS) {
            int e = c0 / 2 + i;
            float2 xx = x2x[e], yy = x2y[e];
            sm.sA[i] = make_float4(xx.x, xx.y, yy.x, yy.y);
            sm.sC[i] = x2z[e];
        }
        __syncthreads();
#pragma unroll 2
        for (int j = 0; j < TILE / 128; ++j) {
            float4 a = sm.sA[lane + 64 * j];
            float2 z = sm.sC[lane + 64 * j];
            v2f ax = {a.x, a.y}, ay = {a.z, a.w}, az = {z.x, z.y};
#pragma unroll
            for (int r = 0; r < RPW; ++r) {
                v2f dx = px[r] - ax, dy = py[r] - ay, dz = pz[r] - az;
                v2f d = dx * dx + dy * dy + dz * dz;
                v2f sd = ls2 * d;
                if (!__all(fmaxf(sd.x, sd.y) < CULL_FULL)) {
                    v2f e2 = {fexp2(sd.x), fexp2(sd.y)};
                    acc[r] += e2;
                }
            }
        }
    }
#pragma unroll
    for (int r = 0; r < RPW; ++r) {
        float s = wave_reduce(acc[r].x + acc[r].y);
        if (lane == 0) {
            int idx = b * NPTS + row0 + r;
            astore(&rLout[idx], 1.0f / (EMD_EPS + s));
            p.remainL[idx] = 1.0f;
        }
    }
}

// ---------------------------------------------------------------- phase: ratioR (sweep t)
template <bool CULL>
__device__ __forceinline__ void phase_ratioR(Smem& sm, const Params& p, float ls2,
                                             const float* __restrict__ rL,
                                             const float* __restrict__ rRprev,
                                             float* __restrict__ rRout,
                                             float* __restrict__ remROut) {
    const int b = blockIdx.y;
    const int tid = threadIdx.x;
    const int wave = tid >> 6;
    const int lane = tid & 63;
    const int col0 = blockIdx.x * RPB + wave * RPW;

    const float* x1 = p.xyz1 + b * 3 * NPTS;
    const float* x2 = p.xyz2 + b * 3 * NPTS;
    const float2* x1x = (const float2*)(x1);
    const float2* x1y = (const float2*)(x1 + NPTS);
    const float2* x1z = (const float2*)(x1 + 2 * NPTS);
    const float2* wLv = (const float2*)(rL + b * NPTS);

    float px[RPW], py[RPW], pz[RPW];
    v2f acc[RPW];
#pragma unroll
    for (int r = 0; r < RPW; ++r) {
        px[r] = x2[col0 + r];
        py[r] = x2[NPTS + col0 + r];
        pz[r] = x2[2 * NPTS + col0 + r];
        acc[r] = (v2f)(0.0f);
    }
    for (int c0 = 0; c0 < NPTS; c0 += TILE) {
        __syncthreads();
        for (int i = tid; i < TILE / 2; i += THREADS) {
            int e = c0 / 2 + i;
            float2 xx = x1x[e], yy = x1y[e], zz = x1z[e], ww = wLv[e];
            sm.sA[i] = make_float4(xx.x, xx.y, yy.x, yy.y);
            sm.sB[i] = make_float4(zz.x, zz.y, ww.x, ww.y);
        }
        __syncthreads();
#pragma unroll 2
        for (int j = 0; j < TILE / 128; ++j) {
            float4 a = sm.sA[lane + 64 * j];
            float4 bq = sm.sB[lane + 64 * j];
            v2f ax = {a.x, a.y}, ay = {a.z, a.w};
            v2f az = {bq.x, bq.y}, aw = {bq.z, bq.w};
#pragma unroll
            for (int r = 0; r < RPW; ++r) {
                v2f dx = px[r] - ax, dy = py[r] - ay, dz = pz[r] - az;
                v2f d = dx * dx + dy * dy + dz * dz;
                v2f sd = ls2 * d;
                bool live = true;
                if (CULL) live = !__all(fmaxf(sd.x, sd.y) < CULL_FULL);
                if (live) {
                    v2f e2 = {fexp2(sd.x), fexp2(sd.y)};
                    acc[r] += e2 * aw;
                }
            }
        }
    }
#pragma unroll
    for (int r = 0; r < RPW; ++r) {
        float s = wave_reduce(acc[r].x + acc[r].y);
        if (lane == 0) {
            int idx = b * NPTS + col0 + r;
            float rv = rRprev ? rRprev[idx] : 1.0f;
            float sumr = rv * s;
            float cons = fminf(rv / (sumr + EMD_EPS), 1.0f);
            astore(&rRout[idx], cons * rv);
            astore(&remROut[idx], fmaxf(0.0f, rv - sumr));
        }
    }
}

// ---------------------------------------------------------------- phase: cost(t) + ratioL(t+1)
template <bool SQ, bool CULL>
__device__ __forceinline__ void phase_cost(Smem& sm, const Params& p,
                                           float ls2, float ls2n,
                                           const float* __restrict__ rR,
                                           const float* __restrict__ w2,
                                           const float* __restrict__ rLin,
                                           float* __restrict__ rLout,
                                           int initCost) {
    const int b = blockIdx.y;
    const int tid = threadIdx.x;
    const int wave = tid >> 6;
    const int lane = tid & 63;
    const int row0 = blockIdx.x * RPB + wave * RPW;

    const float* x1 = p.xyz1 + b * 3 * NPTS;
    const float* x2 = p.xyz2 + b * 3 * NPTS;
    const float2* x2x = (const float2*)(x2);
    const float2* x2y = (const float2*)(x2 + NPTS);
    const float2* x2z = (const float2*)(x2 + 2 * NPTS);
    const float2* wRv = (const float2*)(rR + b * NPTS);
    const float2* w2v = (const float2*)(w2 + b * NPTS);

    float px[RPW], py[RPW], pz[RPW];
    v2f acc_a[RPW], acc_c[RPW], acc_s[RPW];
#pragma unroll
    for (int r = 0; r < RPW; ++r) {
        px[r] = x1[row0 + r];
        py[r] = x1[NPTS + row0 + r];
        pz[r] = x1[2 * NPTS + row0 + r];
        acc_a[r] = (v2f)(0.0f);
        acc_c[r] = (v2f)(0.0f);
        acc_s[r] = (v2f)(0.0f);
    }
    for (int c0 = 0; c0 < NPTS; c0 += TILE) {
        __syncthreads();
        for (int i = tid; i < TILE / 2; i += THREADS) {
            int e = c0 / 2 + i;
            float2 xx = x2x[e], yy = x2y[e], zz = x2z[e];
            float2 wr = wRv[e];
            float2 cw = w2v[e];
            sm.sA[i] = make_float4(xx.x, xx.y, yy.x, yy.y);
            sm.sB[i] = make_float4(zz.x, zz.y, wr.x, wr.y);
            sm.sC[i] = cw;
        }
        __syncthreads();
#pragma unroll 2
        for (int j = 0; j < TILE / 128; ++j) {
            float4 a = sm.sA[lane + 64 * j];
            float4 bq = sm.sB[lane + 64 * j];
            float2 c = sm.sC[lane + 64 * j];
            v2f ax = {a.x, a.y}, ay = {a.z, a.w};
            v2f az = {bq.x, bq.y}, wr = {bq.z, bq.w};
            v2f cw = {c.x, c.y};
#pragma unroll
            for (int r = 0; r < RPW; ++r) {
                v2f dx = px[r] - ax, dy = py[r] - ay, dz = pz[r] - az;
                v2f d = dx * dx + dy * dy + dz * dz;
                if (SQ) {
                    v2f sd = ls2n * d;
                    bool fullskip = false, partskip = false;
                    if (CULL) {
                        float mx = fmaxf(sd.x, sd.y);
                        fullskip = __all(mx < CULL_FULL);
                        partskip = __all(mx < CULL_PART);
                    }
                    if (!fullskip) {
                        v2f e2 = {fexp2(sd.x), fexp2(sd.y)};
                        acc_s[r] += e2 * cw;
                        if (!partskip) {
                            v2f e4 = e2 * e2;
                            v2f er = (e4 * e4) * wr;
                            acc_a[r] += er;
                            v2f sq = {fsqrt(d.x), fsqrt(d.y)};
                            acc_c[r] += er * sq;
                        }
                    }
                } else {
                    v2f sd = ls2 * d;
                    v2f e1 = {fexp2(sd.x), fexp2(sd.y)};
                    v2f er = e1 * wr;
                    acc_s[r] += cw;   // e2 == 1 when ls2n == 0
                    acc_a[r] += er;
                    v2f sq = {fsqrt(d.x), fsqrt(d.y)};
                    acc_c[r] += er * sq;
                }
            }
        }
    }
    float wcost = 0.0f;
#pragma unroll
    for (int r = 0; r < RPW; ++r) {
        float sa = wave_reduce(acc_a[r].x + acc_a[r].y);
        float sc = wave_reduce(acc_c[r].x + acc_c[r].y);
        float ss = wave_reduce(acc_s[r].x + acc_s[r].y);
        if (lane == 0) {
            int idx = b * NPTS + row0 + r;
            float rl = rLin[idx];
            float rem = fmaxf(0.0f, p.remainL[idx] - rl * sa);
            p.remainL[idx] = rem;
            astore(&rLout[idx], rem / (EMD_EPS + ss));
            wcost = fmaf(rl, sc, wcost);
        }
    }
    if (lane == 0) sm.s_cost[wave] = wcost;
    __syncthreads();
    if (tid == 0) {
        float t = sm.s_cost[0] + sm.s_cost[1] + sm.s_cost[2] + sm.s_cost[3];
        int ci = b * NBLK + blockIdx.x;
        astore(&p.cost_part[ci], initCost ? t : aload(&p.cost_part[ci]) + t);
    }
}

// ---------------------------------------------------------------- phase: sum ratioL[9]
__device__ __forceinline__ void phase_sum_ratioL(Smem& sm, const Params& p,
                                                 const float* __restrict__ rL) {
    if (blockIdx.x != 0) return;
    const int b = blockIdx.y;
    const int tid = threadIdx.x;
    float s = 0.0f;
    for (int i = tid; i < NPTS; i += 256) s += rL[b * NPTS + i];
    s = wave_reduce(s);
    if ((tid & 63) == 0) sm.s_cost[tid >> 6] = s;
    __syncthreads();
    if (tid == 0)
        astore(&p.S_L[b], sm.s_cost[0] + sm.s_cost[1] + sm.s_cost[2] + sm.s_cost[3]);
}

// ---------------------------------------------------------------- phase: level-0 cost
__device__ __forceinline__ void phase_cost_l0(Smem& sm, const Params& p,
                                              const float* __restrict__ w2,
                                              const float* __restrict__ rL) {
    const int b = blockIdx.y;
    const int tid = threadIdx.x;
    const int wave = tid >> 6;
    const int lane = tid & 63;
    const int row0 = blockIdx.x * RPB + wave * RPW;
    const float sL = aload(&p.S_L[b]);

    const float* x1 = p.xyz1 + b * 3 * NPTS;
    const float* x2 = p.xyz2 + b * 3 * NPTS;
    const float2* x2x = (const float2*)(x2);
    const float2* x2y = (const float2*)(x2 + NPTS);
    const float2* x2z = (const float2*)(x2 + 2 * NPTS);
    const float2* wRv = (const float2*)(w2 + b * NPTS);

    float px[RPW], py[RPW], pz[RPW];
    v2f acc_c[RPW];
#pragma unroll
    for (int r = 0; r < RPW; ++r) {
        px[r] = x1[row0 + r];
        py[r] = x1[NPTS + row0 + r];
        pz[r] = x1[2 * NPTS + row0 + r];
        acc_c[r] = (v2f)(0.0f);
    }
    for (int c0 = 0; c0 < NPTS; c0 += TILE) {
        __syncthreads();
        for (int i = tid; i < TILE / 2; i += THREADS) {
            int e = c0 / 2 + i;
            float2 xx = x2x[e], yy = x2y[e], zz = x2z[e], rv = wRv[e];
            float wr0 = fminf(rv.x / (rv.x * sL + EMD_EPS), 1.0f) * rv.x;
            float wr1 = fminf(rv.y / (rv.y * sL + EMD_EPS), 1.0f) * rv.y;
            sm.sA[i] = make_float4(xx.x, xx.y, yy.x, yy.y);
            sm.sB[i] = make_float4(zz.x, zz.y, wr0, wr1);
        }
        __syncthreads();
#pragma unroll 2
        for (int j = 0; j < TILE / 128; ++j) {
            float4 a = sm.sA[lane + 64 * j];
            float4 bq = sm.sB[lane + 64 * j];
            v2f ax = {a.x, a.y}, ay = {a.z, a.w};
            v2f az = {bq.x, bq.y}, wr = {bq.z, bq.w};
#pragma unroll
            for (int r = 0; r < RPW; ++r) {
                v2f dx = px[r] - ax, dy = py[r] - ay, dz = pz[r] - az;
                v2f d = dx * dx + dy * dy + dz * dz;
                v2f sq = {fsqrt(d.x), fsqrt(d.y)};
                acc_c[r] += wr * sq;
            }
        }
    }
    float wcost = 0.0f;
#pragma unroll
    for (int r = 0; r < RPW; ++r) {
        float sc = wave_reduce(acc_c[r].x + acc_c[r].y);
        if (lane == 0)
            wcost = fmaf(rL[b * NPTS + row0 + r], sc, wcost);
    }
    if (lane == 0) sm.s_cost[wave] = wcost;
    __syncthreads();
    if (tid == 0) {
        float t = sm.s_cost[0] + sm.s_cost[1] + sm.s_cost[2] + sm.s_cost[3];
        int ci = b * NBLK + blockIdx.x;
        astore(&p.cost_part[ci], aload(&p.cost_part[ci]) + t);
    }
}

// ---------------------------------------------------------------- phase: finalize
__device__ __forceinline__ void phase_final(Smem& sm, const Params& p) {
    if (blockIdx.x != 0 || blockIdx.y != 0) return;
    const int tid = threadIdx.x;
    float s = 0.0f;
    for (int i = tid; i < BATCH * NBLK; i += 256) s += aload(&p.cost_part[i]);
    s = wave_reduce(s);
    if ((tid & 63) == 0) sm.s_cost[tid >> 6] = s;
    __syncthreads();
    if (tid == 0)
        p.out[0] = (sm.s_cost[0] + sm.s_cost[1] + sm.s_cost[2] + sm.s_cost[3]) /
                   ((float)NPTS * (float)BATCH);
}

// ---------------------------------------------------------------- unified persistent kernel
__global__ __launch_bounds__(THREADS, 4) void k_emd_all(Params p) {
    __shared__ Smem sm;
    int bi = 0;
    phase_ratioL0(sm, p, p.ls2[0], p.ratioL[0]);
    gsync(p.bar, bi++);
    for (int t = 0; t < 9; ++t) {
        const float* rRprev = (t == 0) ? nullptr : p.remainR[t - 1];
        if (t < 4)
            phase_ratioR<true>(sm, p, p.ls2[t], p.ratioL[t], rRprev,
                               p.ratioR[t], p.remainR[t]);
        else
            phase_ratioR<false>(sm, p, p.ls2[t], p.ratioL[t], rRprev,
                                p.ratioR[t], p.remainR[t]);
        gsync(p.bar, bi++);
        if (t < 4)
            phase_cost<true, true>(sm, p, p.ls2[t], p.ls2[t + 1], p.ratioR[t],
                                   p.remainR[t], p.ratioL[t], p.ratioL[t + 1], t == 0);
        else if (t < 8)
            phase_cost<true, false>(sm, p, p.ls2[t], p.ls2[t + 1], p.ratioR[t],
                                    p.remainR[t], p.ratioL[t], p.ratioL[t + 1], 0);
        else
            phase_cost<false, false>(sm, p, p.ls2[8], 0.0f, p.ratioR[8],
                                     p.remainR[8], p.ratioL[8], p.ratioL[9], 0);
        gsync(p.bar, bi++);
    }
    phase_sum_ratioL(sm, p, p.ratioL[9]);
    gsync(p.bar, bi++);
    phase_cost_l0(sm, p, p.remainR[8], p.ratioL[9]);
    gsync(p.bar, bi++);
    phase_final(sm, p);
}

// ---------------------------------------------------------------- barrier init
__global__ void k_zero(unsigned* bar) {
    const int n = NB_BAR * BAR_STRIDE;
    for (int i = blockIdx.x * 256 + threadIdx.x; i < n; i += gridDim.x * 256)
        __hip_atomic_store(&bar[i], 0u, __ATOMIC_RELAXED, __HIP_MEMORY_SCOPE_AGENT);
}

// ---------------------------------------------------------------- fallback wrappers
__global__ __launch_bounds__(THREADS, 4) void kw_ratioL0(Params p) {
    __shared__ Smem sm;
    phase_ratioL0(sm, p, p.ls2[0], p.ratioL[0]);
}
__global__ __launch_bounds__(THREADS, 4) void kw_ratioR(Params p, int t) {
    __shared__ Smem sm;
    const float* rRprev = (t == 0) ? nullptr : p.remainR[t - 1];
    if (t < 4) phase_ratioR<true>(sm, p, p.ls2[t], p.ratioL[t], rRprev,
                                  p.ratioR[t], p.remainR[t]);
    else       phase_ratioR<false>(sm, p, p.ls2[t], p.ratioL[t], rRprev,
                                   p.ratioR[t], p.remainR[t]);
}
__global__ __launch_bounds__(THREADS, 4) void kw_cost(Params p, int t) {
    __shared__ Smem sm;
    if (t < 4)
        phase_cost<true, true>(sm, p, p.ls2[t], p.ls2[t + 1], p.ratioR[t],
                               p.remainR[t], p.ratioL[t], p.ratioL[t + 1], t == 0);
    else if (t < 8)
        phase_cost<true, false>(sm, p, p.ls2[t], p.ls2[t + 1], p.ratioR[t],
                                p.remainR[t], p.ratioL[t], p.ratioL[t + 1], 0);
    else
        phase_cost<false, false>(sm, p, p.ls2[8], 0.0f, p.ratioR[8],
                                 p.remainR[8], p.ratioL[8], p.ratioL[9], 0);
}
__global__ __launch_bounds__(THREADS, 4) void kw_sum(Params p) {
    __shared__ Smem sm;
    phase_sum_ratioL(sm, p, p.ratioL[9]);
}
__global__ __launch_bounds__(THREADS, 4) void kw_cost_l0(Params p) {
    __shared__ Smem sm;
    phase_cost_l0(sm, p, p.remainR[8], p.ratioL[9]);
}
__global__ __launch_bounds__(THREADS, 4) void kw_final(Params p) {
    __shared__ Smem sm;
    phase_final(sm, p);
}

extern "C" void kernel_launch(void* const* d_in, const int* in_sizes, int n_in,
                              void* d_out, int out_size, void* d_ws, size_t ws_size,
                              hipStream_t stream) {
    Params p;
    p.xyz1 = (const float*)d_in[0];
    p.xyz2 = (const float*)d_in[1];
    const int BN = BATCH * NPTS;              // 16384 floats per buffer
    const int BUF = BN + 1024;                // + 4KB pad between buffers
    float* ws = (float*)d_ws;
    p.remainL   = ws;                         // BN, block-private
    p.cost_part = ws + BN;                    // 1024
    p.S_L       = p.cost_part + 2048;         // BATCH
    p.bar       = (unsigned*)(p.S_L + 256);   // NB_BAR * BAR_STRIDE u32
    float* vbase = (float*)(p.bar + NB_BAR * BAR_STRIDE) + 256;
    for (int t = 0; t < 10; ++t) p.ratioL[t]  = vbase + t * BUF;
    for (int t = 0; t < 9; ++t)  p.ratioR[t]  = vbase + (10 + t) * BUF;
    for (int t = 0; t < 9; ++t)  p.remainR[t] = vbase + (19 + t) * BUF;
    p.out = (float*)d_out;

    static const double levels[10] = {
        -16384.0, -4096.0, -1024.0, -256.0, -64.0,
        -16.0, -4.0, -1.0, -0.25, 0.0};
    for (int t = 0; t < 10; ++t)
        p.ls2[t] = (float)(levels[t] * 1.4426950408889634);

    dim3 grid(NBLK, BATCH), blk(THREADS);

    static int coop_ok = -1;
    if (coop_ok < 0) {
        int v = 0;
        hipDeviceGetAttribute(&v, hipDeviceAttributeCooperativeLaunch, 0);
        coop_ok = v;
    }

    hipError_t err = hipErrorUnknown;
    if (coop_ok) {
        k_zero<<<64, 256, 0, stream>>>(p.bar);
        void* args[] = {(void*)&p};
        err = hipLaunchCooperativeKernel((void*)k_emd_all, grid, blk, args, 0, stream);
    }
    if (err != hipSuccess) {
        kw_ratioL0<<<grid, blk, 0, stream>>>(p);
        for (int t = 0; t < 9; ++t) {
            kw_ratioR<<<grid, blk, 0, stream>>>(p, t);
            kw_cost<<<grid, blk, 0, stream>>>(p, t);
        }
        kw_sum<<<dim3(1, BATCH), blk, 0, stream>>>(p);
        kw_cost_l0<<<grid, blk, 0, stream>>>(p);
        kw_final<<<dim3(1, 1), blk, 0, stream>>>(p);
    }
}

// Round 9
// 533.007 us; speedup vs baseline: 1.3046x; 1.2302x over previous
//
#include <hip/hip_runtime.h>

// approxmatch EMD (Fan et al.) on MI355X, B=4, N=M=4096, layout (B,3,N).
// Round 15: resident-cloud round.
// R8 post-mortem: TILE 512->1024 neutral -> staging-loop structure itself is
// the idle (per-phase re-stream of all arrays + per-tile syncs + addr math;
// only ~190us of the 352us VALU-busy is algorithm math).
// Fix: exploit cross-phase reuse. 1024-thread blocks (16 waves, RPW=4 ->
// RPB=64), grid 256 = 1 block/CU (coop-resident): stage xyz1+xyz2 (96KB)
// into LDS ONCE for all 21 phases; per-sweep w-arrays staged once per phase
// into 32KB spare LDS (128KB total <= 160KB). Phases are pure compute:
// no tile loops, ONE syncthreads per phase. Same 16 waves/CU occupancy.
// Column order (cp = lane+64j ascending) and all expressions unchanged ->
// bitwise-identical. Barrier arrivals 1024 -> 256 (NGRP 16x16).

#define NPTS 4096
#define BATCH 4
#define EMD_EPS 1e-9f
#define RPW 4             // rows per wave, in registers
#define THREADS 1024      // 16 waves
#define NWAVE (THREADS / 64)
#define RPB (NWAVE * RPW)          // 64 rows per block
#define NBLK (NPTS / RPB)          // 64 row-blocks per batch
#define NBLK_TOTAL (NBLK * BATCH)  // 256 blocks = 1 per CU
#define NJ (NPTS / 128)            // 32 j-groups over all columns

#define GRP_SHIFT 4
#define GRP_SIZE (1 << GRP_SHIFT)      // 16 blocks per barrier group
#define NGRP (NBLK_TOTAL / GRP_SIZE)   // 16 groups
#define BAR_STRIDE 4352                // u32 per barrier instance
#define NB_BAR 24                      // 21 used

#define CULL_FULL -160.0f  // exp2(x) == +0.0f for all x < -160
#define CULL_PART -40.0f   // ((2^x)^2)^2 == +0.0f for all x < -40

typedef float v2f __attribute__((ext_vector_type(2)));

struct Params {
    const float* xyz1;
    const float* xyz2;
    float* remainL;          // block-private: normal access
    float* cost_part;        // agent (cross-XCD read at finalize)
    float* S_L;              // agent
    float* out;
    unsigned* bar;
    float* ratioL[10];       // versioned: ratioL[t] written end of sweep t-1
    float* ratioR[9];        // versioned per sweep
    float* remainR[9];       // versioned per sweep
    float ls2[10];
};

struct Smem {
    alignas(16) float x1x[NPTS];   // persistent: whole-kernel
    alignas(16) float x1y[NPTS];
    alignas(16) float x1z[NPTS];
    alignas(16) float x2x[NPTS];
    alignas(16) float x2y[NPTS];
    alignas(16) float x2z[NPTS];
    alignas(16) float sW[NPTS];    // per-phase: ratioL / ratioR / wr_l0
    alignas(16) float sV[NPTS];    // per-phase: remainR (cost phases)
    float s_cost[NWAVE];
};

// ---------------- agent-scope (LLC-routed, L2-bypassing) accessors
__device__ __forceinline__ float aload(const float* p_) {
    return __hip_atomic_load((float*)p_, __ATOMIC_RELAXED, __HIP_MEMORY_SCOPE_AGENT);
}
__device__ __forceinline__ void astore(float* p_, float v) {
    __hip_atomic_store(p_, v, __ATOMIC_RELAXED, __HIP_MEMORY_SCOPE_AGENT);
}
__device__ __forceinline__ unsigned au_add(unsigned* p_, unsigned v) {
    return __hip_atomic_fetch_add(p_, v, __ATOMIC_RELAXED, __HIP_MEMORY_SCOPE_AGENT);
}
__device__ __forceinline__ unsigned au_load(const unsigned* p_) {
    return __hip_atomic_load((unsigned*)p_, __ATOMIC_RELAXED, __HIP_MEMORY_SCOPE_AGENT);
}
__device__ __forceinline__ void au_store(unsigned* p_, unsigned v) {
    __hip_atomic_store(p_, v, __ATOMIC_RELAXED, __HIP_MEMORY_SCOPE_AGENT);
}

// ---------------- two-level grid barrier (relaxed agent atomics, striped)
__device__ __forceinline__ void gsync(unsigned* barbase, int idx) {
    __syncthreads();
    if (threadIdx.x == 0) {
        unsigned* B = barbase + idx * BAR_STRIDE;
        const int bid = blockIdx.y * NBLK + blockIdx.x;
        const int grp = bid >> GRP_SHIFT;
        unsigned* gc   = B + grp * 32;
        unsigned* root = B + NGRP * 32;
        unsigned* gr   = B + NGRP * 32 + 32 + grp * 32;
        unsigned old = au_add(gc, 1u);
        if (old == GRP_SIZE - 1u) {
            unsigned r = au_add(root, 1u) + 1u;
            while (r < (unsigned)NGRP) {
                __builtin_amdgcn_s_sleep(4);
                r = au_load(root);
            }
            au_store(gr, 1u);
        } else {
            while (au_load(gr) == 0u)
                __builtin_amdgcn_s_sleep(4);
        }
        asm volatile("" ::: "memory");
    }
    __syncthreads();
}

__device__ __forceinline__ float fexp2(float x) {
#if __has_builtin(__builtin_amdgcn_exp2f)
    return __builtin_amdgcn_exp2f(x);
#else
    return exp2f(x);
#endif
}
__device__ __forceinline__ float fsqrt(float x) {
#if __has_builtin(__builtin_amdgcn_sqrtf)
    return __builtin_amdgcn_sqrtf(x);
#else
    return __sqrtf(x);
#endif
}

__device__ __forceinline__ float wave_reduce(float v) {
    v += __shfl_xor(v, 32);
    v += __shfl_xor(v, 16);
    v += __shfl_xor(v, 8);
    v += __shfl_xor(v, 4);
    v += __shfl_xor(v, 2);
    v += __shfl_xor(v, 1);
    return v;
}

// ---------------- one-time xyz staging (96KB, whole kernel lifetime)
__device__ __forceinline__ void stage_xyz(Smem& sm, const Params& p) {
    const int b = blockIdx.y;
    const int i = threadIdx.x;          // THREADS == NPTS/4 exactly
    const float4* g1 = (const float4*)(p.xyz1 + b * 3 * NPTS);
    const float4* g2 = (const float4*)(p.xyz2 + b * 3 * NPTS);
    ((float4*)sm.x1x)[i] = g1[i];
    ((float4*)sm.x1y)[i] = g1[NPTS / 4 + i];
    ((float4*)sm.x1z)[i] = g1[2 * (NPTS / 4) + i];
    ((float4*)sm.x2x)[i] = g2[i];
    ((float4*)sm.x2y)[i] = g2[NPTS / 4 + i];
    ((float4*)sm.x2z)[i] = g2[2 * (NPTS / 4) + i];
    __syncthreads();
}

// ---------------- per-phase w staging (one float4 per thread per array)
__device__ __forceinline__ void stage_w1(Smem& sm, const float* gw) {
    ((float4*)sm.sW)[threadIdx.x] = ((const float4*)gw)[threadIdx.x];
    __syncthreads();
}
__device__ __forceinline__ void stage_w2(Smem& sm, const float* gw, const float* gv) {
    ((float4*)sm.sW)[threadIdx.x] = ((const float4*)gw)[threadIdx.x];
    ((float4*)sm.sV)[threadIdx.x] = ((const float4*)gv)[threadIdx.x];
    __syncthreads();
}

// ---------------------------------------------------------------- phase: sweep-0 ratioL
__device__ __forceinline__ void phase_ratioL0(Smem& sm, const Params& p, float ls2,
                                              float* __restrict__ rLout) {
    const int b = blockIdx.y;
    const int tid = threadIdx.x;
    const int wave = tid >> 6;
    const int lane = tid & 63;
    const int row0 = blockIdx.x * RPB + wave * RPW;

    float px[RPW], py[RPW], pz[RPW];
    v2f acc[RPW];
#pragma unroll
    for (int r = 0; r < RPW; ++r) {
        px[r] = sm.x1x[row0 + r];
        py[r] = sm.x1y[row0 + r];
        pz[r] = sm.x1z[row0 + r];
        acc[r] = (v2f)(0.0f);
    }
    const v2f* vx = (const v2f*)sm.x2x;
    const v2f* vy = (const v2f*)sm.x2y;
    const v2f* vz = (const v2f*)sm.x2z;
#pragma unroll 2
    for (int j = 0; j < NJ; ++j) {
        int cp = lane + 64 * j;
        v2f ax = vx[cp], ay = vy[cp], az = vz[cp];
#pragma unroll
        for (int r = 0; r < RPW; ++r) {
            v2f dx = px[r] - ax, dy = py[r] - ay, dz = pz[r] - az;
            v2f d = dx * dx + dy * dy + dz * dz;
            v2f sd = ls2 * d;
            if (!__all(fmaxf(sd.x, sd.y) < CULL_FULL)) {
                v2f e2 = {fexp2(sd.x), fexp2(sd.y)};
                acc[r] += e2;
            }
        }
    }
#pragma unroll
    for (int r = 0; r < RPW; ++r) {
        float s = wave_reduce(acc[r].x + acc[r].y);
        if (lane == 0) {
            int idx = b * NPTS + row0 + r;
            astore(&rLout[idx], 1.0f / (EMD_EPS + s));
            p.remainL[idx] = 1.0f;
        }
    }
}

// ---------------------------------------------------------------- phase: ratioR (sweep t)
// rows from xyz2 (LDS), cols from xyz1 (LDS), ratioL staged in sW.
template <bool CULL>
__device__ __forceinline__ void phase_ratioR(Smem& sm, const Params& p, float ls2,
                                             const float* __restrict__ rL,
                                             const float* __restrict__ rRprev,
                                             float* __restrict__ rRout,
                                             float* __restrict__ remROut) {
    const int b = blockIdx.y;
    const int tid = threadIdx.x;
    const int wave = tid >> 6;
    const int lane = tid & 63;
    const int col0 = blockIdx.x * RPB + wave * RPW;

    stage_w1(sm, rL + b * NPTS);

    float px[RPW], py[RPW], pz[RPW];
    v2f acc[RPW];
#pragma unroll
    for (int r = 0; r < RPW; ++r) {
        px[r] = sm.x2x[col0 + r];
        py[r] = sm.x2y[col0 + r];
        pz[r] = sm.x2z[col0 + r];
        acc[r] = (v2f)(0.0f);
    }
    const v2f* vx = (const v2f*)sm.x1x;
    const v2f* vy = (const v2f*)sm.x1y;
    const v2f* vz = (const v2f*)sm.x1z;
    const v2f* vw = (const v2f*)sm.sW;
#pragma unroll 2
    for (int j = 0; j < NJ; ++j) {
        int cp = lane + 64 * j;
        v2f ax = vx[cp], ay = vy[cp], az = vz[cp], aw = vw[cp];
#pragma unroll
        for (int r = 0; r < RPW; ++r) {
            v2f dx = px[r] - ax, dy = py[r] - ay, dz = pz[r] - az;
            v2f d = dx * dx + dy * dy + dz * dz;
            v2f sd = ls2 * d;
            bool live = true;
            if (CULL) live = !__all(fmaxf(sd.x, sd.y) < CULL_FULL);
            if (live) {
                v2f e2 = {fexp2(sd.x), fexp2(sd.y)};
                acc[r] += e2 * aw;
            }
        }
    }
#pragma unroll
    for (int r = 0; r < RPW; ++r) {
        float s = wave_reduce(acc[r].x + acc[r].y);
        if (lane == 0) {
            int idx = b * NPTS + col0 + r;
            float rv = rRprev ? rRprev[idx] : 1.0f;
            float sumr = rv * s;
            float cons = fminf(rv / (sumr + EMD_EPS), 1.0f);
            astore(&rRout[idx], cons * rv);
            astore(&remROut[idx], fmaxf(0.0f, rv - sumr));
        }
    }
}

// ---------------------------------------------------------------- phase: cost(t) + ratioL(t+1)
// rows from xyz1 (LDS), cols from xyz2 (LDS), ratioR in sW, remainR in sV.
template <bool SQ, bool CULL>
__device__ __forceinline__ void phase_cost(Smem& sm, const Params& p,
                                           float ls2, float ls2n,
                                           const float* __restrict__ rR,
                                           const float* __restrict__ w2,
                                           const float* __restrict__ rLin,
                                           float* __restrict__ rLout,
                                           int initCost) {
    const int b = blockIdx.y;
    const int tid = threadIdx.x;
    const int wave = tid >> 6;
    const int lane = tid & 63;
    const int row0 = blockIdx.x * RPB + wave * RPW;

    stage_w2(sm, rR + b * NPTS, w2 + b * NPTS);

    float px[RPW], py[RPW], pz[RPW];
    v2f acc_a[RPW], acc_c[RPW], acc_s[RPW];
#pragma unroll
    for (int r = 0; r < RPW; ++r) {
        px[r] = sm.x1x[row0 + r];
        py[r] = sm.x1y[row0 + r];
        pz[r] = sm.x1z[row0 + r];
        acc_a[r] = (v2f)(0.0f);
        acc_c[r] = (v2f)(0.0f);
        acc_s[r] = (v2f)(0.0f);
    }
    const v2f* vx = (const v2f*)sm.x2x;
    const v2f* vy = (const v2f*)sm.x2y;
    const v2f* vz = (const v2f*)sm.x2z;
    const v2f* vw = (const v2f*)sm.sW;
    const v2f* vv = (const v2f*)sm.sV;
#pragma unroll 2
    for (int j = 0; j < NJ; ++j) {
        int cp = lane + 64 * j;
        v2f ax = vx[cp], ay = vy[cp], az = vz[cp];
        v2f wr = vw[cp], cw = vv[cp];
#pragma unroll
        for (int r = 0; r < RPW; ++r) {
            v2f dx = px[r] - ax, dy = py[r] - ay, dz = pz[r] - az;
            v2f d = dx * dx + dy * dy + dz * dz;
            if (SQ) {
                v2f sd = ls2n * d;
                bool fullskip = false, partskip = false;
                if (CULL) {
                    float mx = fmaxf(sd.x, sd.y);
                    fullskip = __all(mx < CULL_FULL);
                    partskip = __all(mx < CULL_PART);
                }
                if (!fullskip) {
                    v2f e2 = {fexp2(sd.x), fexp2(sd.y)};
                    acc_s[r] += e2 * cw;
                    if (!partskip) {
                        v2f e4 = e2 * e2;
                        v2f er = (e4 * e4) * wr;
                        acc_a[r] += er;
                        v2f sq = {fsqrt(d.x), fsqrt(d.y)};
                        acc_c[r] += er * sq;
                    }
                }
            } else {
                v2f sd = ls2 * d;
                v2f e1 = {fexp2(sd.x), fexp2(sd.y)};
                v2f er = e1 * wr;
                acc_s[r] += cw;   // e2 == 1 when ls2n == 0
                acc_a[r] += er;
                v2f sq = {fsqrt(d.x), fsqrt(d.y)};
                acc_c[r] += er * sq;
            }
        }
    }
    float wcost = 0.0f;
#pragma unroll
    for (int r = 0; r < RPW; ++r) {
        float sa = wave_reduce(acc_a[r].x + acc_a[r].y);
        float sc = wave_reduce(acc_c[r].x + acc_c[r].y);
        float ss = wave_reduce(acc_s[r].x + acc_s[r].y);
        if (lane == 0) {
            int idx = b * NPTS + row0 + r;
            float rl = rLin[idx];
            float rem = fmaxf(0.0f, p.remainL[idx] - rl * sa);
            p.remainL[idx] = rem;
            astore(&rLout[idx], rem / (EMD_EPS + ss));
            wcost = fmaf(rl, sc, wcost);
        }
    }
    if (lane == 0) sm.s_cost[wave] = wcost;
    __syncthreads();
    if (tid == 0) {
        float t = 0.0f;
        for (int w = 0; w < NWAVE; ++w) t += sm.s_cost[w];
        int ci = b * NBLK + blockIdx.x;
        astore(&p.cost_part[ci], initCost ? t : aload(&p.cost_part[ci]) + t);
    }
}

// ---------------------------------------------------------------- phase: sum ratioL[9]
__device__ __forceinline__ void phase_sum_ratioL(Smem& sm, const Params& p,
                                                 const float* __restrict__ rL) {
    if (blockIdx.x != 0) return;
    const int b = blockIdx.y;
    const int tid = threadIdx.x;
    float s = 0.0f;
    for (int i = tid; i < NPTS; i += THREADS) s += rL[b * NPTS + i];
    s = wave_reduce(s);
    if ((tid & 63) == 0) sm.s_cost[tid >> 6] = s;
    __syncthreads();
    if (tid == 0) {
        float t = 0.0f;
        for (int w = 0; w < NWAVE; ++w) t += sm.s_cost[w];
        astore(&p.S_L[b], t);
    }
}

// ---------------------------------------------------------------- phase: level-0 cost
// wr transformed during staging (same scalar expression per element as R4).
__device__ __forceinline__ void phase_cost_l0(Smem& sm, const Params& p,
                                              const float* __restrict__ w2,
                                              const float* __restrict__ rL) {
    const int b = blockIdx.y;
    const int tid = threadIdx.x;
    const int wave = tid >> 6;
    const int lane = tid & 63;
    const int row0 = blockIdx.x * RPB + wave * RPW;
    const float sL = aload(&p.S_L[b]);

    {   // stage transformed ratioR_l0 into sW
        float4 rv = ((const float4*)(w2 + b * NPTS))[tid];
        float4 w;
        w.x = fminf(rv.x / (rv.x * sL + EMD_EPS), 1.0f) * rv.x;
        w.y = fminf(rv.y / (rv.y * sL + EMD_EPS), 1.0f) * rv.y;
        w.z = fminf(rv.z / (rv.z * sL + EMD_EPS), 1.0f) * rv.z;
        w.w = fminf(rv.w / (rv.w * sL + EMD_EPS), 1.0f) * rv.w;
        ((float4*)sm.sW)[tid] = w;
        __syncthreads();
    }

    float px[RPW], py[RPW], pz[RPW];
    v2f acc_c[RPW];
#pragma unroll
    for (int r = 0; r < RPW; ++r) {
        px[r] = sm.x1x[row0 + r];
        py[r] = sm.x1y[row0 + r];
        pz[r] = sm.x1z[row0 + r];
        acc_c[r] = (v2f)(0.0f);
    }
    const v2f* vx = (const v2f*)sm.x2x;
    const v2f* vy = (const v2f*)sm.x2y;
    const v2f* vz = (const v2f*)sm.x2z;
    const v2f* vw = (const v2f*)sm.sW;
#pragma unroll 2
    for (int j = 0; j < NJ; ++j) {
        int cp = lane + 64 * j;
        v2f ax = vx[cp], ay = vy[cp], az = vz[cp], wr = vw[cp];
#pragma unroll
        for (int r = 0; r < RPW; ++r) {
            v2f dx = px[r] - ax, dy = py[r] - ay, dz = pz[r] - az;
            v2f d = dx * dx + dy * dy + dz * dz;
            v2f sq = {fsqrt(d.x), fsqrt(d.y)};
            acc_c[r] += wr * sq;
        }
    }
    float wcost = 0.0f;
#pragma unroll
    for (int r = 0; r < RPW; ++r) {
        float sc = wave_reduce(acc_c[r].x + acc_c[r].y);
        if (lane == 0)
            wcost = fmaf(rL[b * NPTS + row0 + r], sc, wcost);
    }
    if (lane == 0) sm.s_cost[wave] = wcost;
    __syncthreads();
    if (tid == 0) {
        float t = 0.0f;
        for (int w = 0; w < NWAVE; ++w) t += sm.s_cost[w];
        int ci = b * NBLK + blockIdx.x;
        astore(&p.cost_part[ci], aload(&p.cost_part[ci]) + t);
    }
}

// ---------------------------------------------------------------- phase: finalize
__device__ __forceinline__ void phase_final(Smem& sm, const Params& p) {
    if (blockIdx.x != 0 || blockIdx.y != 0) return;
    const int tid = threadIdx.x;
    float s = 0.0f;
    for (int i = tid; i < BATCH * NBLK; i += THREADS) s += aload(&p.cost_part[i]);
    s = wave_reduce(s);
    if ((tid & 63) == 0) sm.s_cost[tid >> 6] = s;
    __syncthreads();
    if (tid == 0) {
        float t = 0.0f;
        for (int w = 0; w < NWAVE; ++w) t += sm.s_cost[w];
        p.out[0] = t / ((float)NPTS * (float)BATCH);
    }
}

// ---------------------------------------------------------------- unified persistent kernel
__global__ __launch_bounds__(THREADS, 4) void k_emd_all(Params p) {
    __shared__ Smem sm;
    stage_xyz(sm, p);
    int bi = 0;
    phase_ratioL0(sm, p, p.ls2[0], p.ratioL[0]);
    gsync(p.bar, bi++);
    for (int t = 0; t < 9; ++t) {
        const float* rRprev = (t == 0) ? nullptr : p.remainR[t - 1];
        if (t < 4)
            phase_ratioR<true>(sm, p, p.ls2[t], p.ratioL[t], rRprev,
                               p.ratioR[t], p.remainR[t]);
        else
            phase_ratioR<false>(sm, p, p.ls2[t], p.ratioL[t], rRprev,
                                p.ratioR[t], p.remainR[t]);
        gsync(p.bar, bi++);
        if (t < 4)
            phase_cost<true, true>(sm, p, p.ls2[t], p.ls2[t + 1], p.ratioR[t],
                                   p.remainR[t], p.ratioL[t], p.ratioL[t + 1], t == 0);
        else if (t < 8)
            phase_cost<true, false>(sm, p, p.ls2[t], p.ls2[t + 1], p.ratioR[t],
                                    p.remainR[t], p.ratioL[t], p.ratioL[t + 1], 0);
        else
            phase_cost<false, false>(sm, p, p.ls2[8], 0.0f, p.ratioR[8],
                                     p.remainR[8], p.ratioL[8], p.ratioL[9], 0);
        gsync(p.bar, bi++);
    }
    phase_sum_ratioL(sm, p, p.ratioL[9]);
    gsync(p.bar, bi++);
    phase_cost_l0(sm, p, p.remainR[8], p.ratioL[9]);
    gsync(p.bar, bi++);
    phase_final(sm, p);
}

// ---------------------------------------------------------------- barrier init
__global__ void k_zero(unsigned* bar) {
    const int n = NB_BAR * BAR_STRIDE;
    for (int i = blockIdx.x * 256 + threadIdx.x; i < n; i += gridDim.x * 256)
        __hip_atomic_store(&bar[i], 0u, __ATOMIC_RELAXED, __HIP_MEMORY_SCOPE_AGENT);
}

// ---------------------------------------------------------------- fallback wrappers
__global__ __launch_bounds__(THREADS, 4) void kw_ratioL0(Params p) {
    __shared__ Smem sm;
    stage_xyz(sm, p);
    phase_ratioL0(sm, p, p.ls2[0], p.ratioL[0]);
}
__global__ __launch_bounds__(THREADS, 4) void kw_ratioR(Params p, int t) {
    __shared__ Smem sm;
    stage_xyz(sm, p);
    const float* rRprev = (t == 0) ? nullptr : p.remainR[t - 1];
    if (t < 4) phase_ratioR<true>(sm, p, p.ls2[t], p.ratioL[t], rRprev,
                                  p.ratioR[t], p.remainR[t]);
    else       phase_ratioR<false>(sm, p, p.ls2[t], p.ratioL[t], rRprev,
                                   p.ratioR[t], p.remainR[t]);
}
__global__ __launch_bounds__(THREADS, 4) void kw_cost(Params p, int t) {
    __shared__ Smem sm;
    stage_xyz(sm, p);
    if (t < 4)
        phase_cost<true, true>(sm, p, p.ls2[t], p.ls2[t + 1], p.ratioR[t],
                               p.remainR[t], p.ratioL[t], p.ratioL[t + 1], t == 0);
    else if (t < 8)
        phase_cost<true, false>(sm, p, p.ls2[t], p.ls2[t + 1], p.ratioR[t],
                                p.remainR[t], p.ratioL[t], p.ratioL[t + 1], 0);
    else
        phase_cost<false, false>(sm, p, p.ls2[8], 0.0f, p.ratioR[8],
                                 p.remainR[8], p.ratioL[8], p.ratioL[9], 0);
}
__global__ __launch_bounds__(THREADS, 4) void kw_sum(Params p) {
    __shared__ Smem sm;
    phase_sum_ratioL(sm, p, p.ratioL[9]);
}
__global__ __launch_bounds__(THREADS, 4) void kw_cost_l0(Params p) {
    __shared__ Smem sm;
    stage_xyz(sm, p);
    phase_cost_l0(sm, p, p.remainR[8], p.ratioL[9]);
}
__global__ __launch_bounds__(THREADS, 4) void kw_final(Params p) {
    __shared__ Smem sm;
    phase_final(sm, p);
}

extern "C" void kernel_launch(void* const* d_in, const int* in_sizes, int n_in,
                              void* d_out, int out_size, void* d_ws, size_t ws_size,
                              hipStream_t stream) {
    Params p;
    p.xyz1 = (const float*)d_in[0];
    p.xyz2 = (const float*)d_in[1];
    const int BN = BATCH * NPTS;              // 16384 floats per buffer
    const int BUF = BN + 1024;                // + 4KB pad between buffers
    float* ws = (float*)d_ws;
    p.remainL   = ws;                         // BN, block-private
    p.cost_part = ws + BN;                    // 256
    p.S_L       = p.cost_part + 2048;         // BATCH
    p.bar       = (unsigned*)(p.S_L + 256);   // NB_BAR * BAR_STRIDE u32
    float* vbase = (float*)(p.bar + NB_BAR * BAR_STRIDE) + 256;
    for (int t = 0; t < 10; ++t) p.ratioL[t]  = vbase + t * BUF;
    for (int t = 0; t < 9; ++t)  p.ratioR[t]  = vbase + (10 + t) * BUF;
    for (int t = 0; t < 9; ++t)  p.remainR[t] = vbase + (19 + t) * BUF;
    p.out = (float*)d_out;

    static const double levels[10] = {
        -16384.0, -4096.0, -1024.0, -256.0, -64.0,
        -16.0, -4.0, -1.0, -0.25, 0.0};
    for (int t = 0; t < 10; ++t)
        p.ls2[t] = (float)(levels[t] * 1.4426950408889634);

    dim3 grid(NBLK, BATCH), blk(THREADS);

    static int coop_ok = -1;
    if (coop_ok < 0) {
        int v = 0;
        hipDeviceGetAttribute(&v, hipDeviceAttributeCooperativeLaunch, 0);
        coop_ok = v;
    }

    hipError_t err = hipErrorUnknown;
    if (coop_ok) {
        k_zero<<<64, 256, 0, stream>>>(p.bar);
        void* args[] = {(void*)&p};
        err = hipLaunchCooperativeKernel((void*)k_emd_all, grid, blk, args, 0, stream);
    }
    if (err != hipSuccess) {
        kw_ratioL0<<<grid, blk, 0, stream>>>(p);
        for (int t = 0; t < 9; ++t) {
            kw_ratioR<<<grid, blk, 0, stream>>>(p, t);
            kw_cost<<<grid, blk, 0, stream>>>(p, t);
        }
        kw_sum<<<dim3(1, BATCH), blk, 0, stream>>>(p);
        kw_cost_l0<<<grid, blk, 0, stream>>>(p);
        kw_final<<<dim3(1, 1), blk, 0, stream>>>(p);
    }
}